// Round 5
// baseline (663.769 us; speedup 1.0000x reference)
//
#include <hip/hip_runtime.h>
#include <cmath>

#define SS 45

typedef __attribute__((ext_vector_type(8))) short short8;
typedef __attribute__((ext_vector_type(4))) float float4v;

__device__ inline unsigned short bf16r(float f) {
    unsigned int u = __float_as_uint(f);
    unsigned int r = (u + 0x7fff + ((u >> 16) & 1)) >> 16;
    return (unsigned short)r;
}

// ---- x -> xh (bf16 RTN) + xl (bf16 RTN of residual) ---------------------------
__global__ __launch_bounds__(256) void convx2_kernel(
    const float4* __restrict__ x4, ushort4* __restrict__ xh4, ushort4* __restrict__ xl4)
{
    int i = blockIdx.x * 256 + threadIdx.x;   // 2,097,152
    float4 v = x4[i];
    float fv[4] = {v.x, v.y, v.z, v.w};
    ushort4 h, l;
    unsigned short hh[4], ll[4];
    #pragma unroll
    for (int e = 0; e < 4; e++) {
        hh[e] = bf16r(fv[e]);
        float fh = __uint_as_float((unsigned)hh[e] << 16);
        ll[e] = bf16r(fv[e] - fh);
    }
    h.x = hh[0]; h.y = hh[1]; h.z = hh[2]; h.w = hh[3];
    l.x = ll[0]; l.y = ll[1]; l.z = ll[2]; l.w = ll[3];
    xh4[i] = h; xl4[i] = l;
}

// ---- Wq/Wk/Wv -> transposed bf16 hi/lo: WT[z][n][k], z in {0:q,1:k,2:v} -------
__global__ __launch_bounds__(256) void convw2_kernel(
    const float* __restrict__ Wq, const float* __restrict__ Wk, const float* __restrict__ Wv,
    unsigned short* __restrict__ WTh, unsigned short* __restrict__ WTl)
{
    const float* W = (blockIdx.y == 0) ? Wq : (blockIdx.y == 1) ? Wk : Wv;
    unsigned short* th = WTh + (size_t)blockIdx.y * 512 * 512;
    unsigned short* tl = WTl + (size_t)blockIdx.y * 512 * 512;
    __shared__ float t[32][33];
    int bx = blockIdx.x & 15, by = blockIdx.x >> 4;
    int tx = threadIdx.x & 31, ty = threadIdx.x >> 5;
    for (int i = ty; i < 32; i += 8) t[i][tx] = W[(size_t)(by * 32 + i) * 512 + bx * 32 + tx];
    __syncthreads();
    for (int i = ty; i < 32; i += 8) {
        float f = t[tx][i];   // W[k = by*32+tx][n = bx*32+i]
        unsigned short h = bf16r(f);
        float fh = __uint_as_float((unsigned)h << 16);
        unsigned short lo = bf16r(f - fh);
        th[(size_t)(bx * 32 + i) * 512 + by * 32 + tx] = h;
        tl[(size_t)(bx * 32 + i) * 512 + by * 32 + tx] = lo;
    }
}

// ---- fused Q,K projection, split-bf16 MFMA, pre-split A -----------------------
// grid (128, 8); block 128m x 64n; wave 64m x 32n. 4 blocks/CU.
__global__ __launch_bounds__(256, 4) void qk2_kernel(
    const unsigned short* __restrict__ Xh, const unsigned short* __restrict__ Xl,
    const unsigned short* __restrict__ WTh, const unsigned short* __restrict__ WTl,
    float* __restrict__ Q, float* __restrict__ K)
{
    int wave = threadIdx.x >> 6;
    int lane = threadIdx.x & 63;
    int m0 = blockIdx.x * 128 + (wave >> 1) * 64;
    int n0 = blockIdx.y * 64 + (wave & 1) * 32;
    int fr = lane & 15;
    int kq = (lane >> 4) * 8;
    const unsigned short* Bqh = WTh;
    const unsigned short* Bql = WTl;
    const unsigned short* Bkh = WTh + 512 * 512;
    const unsigned short* Bkl = WTl + 512 * 512;

    float4v accq[4][2], acck[4][2];
    #pragma unroll
    for (int i = 0; i < 4; i++)
        #pragma unroll
        for (int j = 0; j < 2; j++) {
            accq[i][j] = (float4v){0.f, 0.f, 0.f, 0.f};
            acck[i][j] = (float4v){0.f, 0.f, 0.f, 0.f};
        }

    for (int k0 = 0; k0 < 512; k0 += 32) {
        short8 ah[4], al[4];
        #pragma unroll
        for (int i = 0; i < 4; i++) {
            size_t aoff = (size_t)(m0 + i * 16 + fr) * 512 + k0 + kq;
            ah[i] = *(const short8*)(Xh + aoff);
            al[i] = *(const short8*)(Xl + aoff);
        }
        #pragma unroll
        for (int j = 0; j < 2; j++) {
            size_t boff = (size_t)(n0 + j * 16 + fr) * 512 + k0 + kq;
            short8 bqh = *(const short8*)(Bqh + boff);
            short8 bql = *(const short8*)(Bql + boff);
            short8 bkh = *(const short8*)(Bkh + boff);
            short8 bkl = *(const short8*)(Bkl + boff);
            #pragma unroll
            for (int i = 0; i < 4; i++) {
                accq[i][j] = __builtin_amdgcn_mfma_f32_16x16x32_bf16(ah[i], bqh, accq[i][j], 0, 0, 0);
                accq[i][j] = __builtin_amdgcn_mfma_f32_16x16x32_bf16(ah[i], bql, accq[i][j], 0, 0, 0);
                accq[i][j] = __builtin_amdgcn_mfma_f32_16x16x32_bf16(al[i], bqh, accq[i][j], 0, 0, 0);
                acck[i][j] = __builtin_amdgcn_mfma_f32_16x16x32_bf16(ah[i], bkh, acck[i][j], 0, 0, 0);
                acck[i][j] = __builtin_amdgcn_mfma_f32_16x16x32_bf16(ah[i], bkl, acck[i][j], 0, 0, 0);
                acck[i][j] = __builtin_amdgcn_mfma_f32_16x16x32_bf16(al[i], bkh, acck[i][j], 0, 0, 0);
            }
        }
    }
    // C/D layout: col = lane&15, row = (lane>>4)*4 + reg
    int rbase = (lane >> 4) * 4, ccol = lane & 15;
    #pragma unroll
    for (int i = 0; i < 4; i++)
        #pragma unroll
        for (int j = 0; j < 2; j++) {
            int c = n0 + j * 16 + ccol;
            int h = c >> 6, d = c & 63;
            #pragma unroll
            for (int r = 0; r < 4; r++) {
                int rg = m0 + i * 16 + rbase + r;
                int bb = rg >> 12, l = rg & 4095;
                size_t off = ((size_t)(bb * 8 + h) * 4096 + l) * 64 + d;
                Q[off] = accq[i][j][r];
                K[off] = acck[i][j][r];
            }
        }
}

// ---- V GEMM via bf16 MFMA, pre-split A (hi only) ------------------------------
__global__ __launch_bounds__(256, 4) void vgemm_kernel(
    const unsigned short* __restrict__ Xh,
    const unsigned short* __restrict__ BTh,   // WT z=2 (hi)
    float* __restrict__ V)
{
    int wave = threadIdx.x >> 6;
    int lane = threadIdx.x & 63;
    int m0 = blockIdx.x * 128 + (wave >> 1) * 64;
    int n0 = blockIdx.y * 64 + (wave & 1) * 32;
    int fr = lane & 15;
    int kq = (lane >> 4) * 8;

    float4v acc[4][2];
    #pragma unroll
    for (int i = 0; i < 4; i++)
        #pragma unroll
        for (int j = 0; j < 2; j++) acc[i][j] = (float4v){0.f, 0.f, 0.f, 0.f};

    for (int k0 = 0; k0 < 512; k0 += 32) {
        short8 a[4], b[2];
        #pragma unroll
        for (int i = 0; i < 4; i++)
            a[i] = *(const short8*)(Xh + (size_t)(m0 + i * 16 + fr) * 512 + k0 + kq);
        #pragma unroll
        for (int j = 0; j < 2; j++)
            b[j] = *(const short8*)(BTh + (size_t)(n0 + j * 16 + fr) * 512 + k0 + kq);
        #pragma unroll
        for (int i = 0; i < 4; i++)
            #pragma unroll
            for (int j = 0; j < 2; j++)
                acc[i][j] = __builtin_amdgcn_mfma_f32_16x16x32_bf16(a[i], b[j], acc[i][j], 0, 0, 0);
    }
    int rbase = (lane >> 4) * 4, ccol = lane & 15;
    #pragma unroll
    for (int i = 0; i < 4; i++)
        #pragma unroll
        for (int j = 0; j < 2; j++) {
            int c = n0 + j * 16 + ccol;
            int h = c >> 6, d = c & 63;
            #pragma unroll
            for (int r = 0; r < 4; r++) {
                int rg = m0 + i * 16 + rbase + r;
                int bb = rg >> 12, l = rg & 4095;
                V[((size_t)(bb * 8 + h) * 4096 + l) * 64 + d] = acc[i][j][r];
            }
        }
}

// ---------------- M = max_s(q.k_samp) - mean_s(q.k_samp), fp32 ----------------
__global__ __launch_bounds__(256) void m_kernel(
    const float* __restrict__ Q, const float* __restrict__ K,
    const int* __restrict__ idx, float* __restrict__ M)
{
    int inst = blockIdx.x * 4 + (threadIdx.x >> 6);   // bh*4096 + l
    int lane = threadIdx.x & 63;
    int g = lane >> 4;
    int t = lane & 15;
    int bh = inst >> 12;
    int l = inst & 4095;
    float4 qv = *(const float4*)(Q + (size_t)inst * 64 + t * 4);
    const float* kb = K + (size_t)bh * 4096 * 64;
    const int* irow = idx + (size_t)l * SS;
    int jv[12];
    #pragma unroll
    for (int it = 0; it < 12; it++) {
        int s = it * 4 + g;
        jv[it] = irow[(s < SS) ? s : 0];
    }
    float maxv = -1e30f, sum = 0.f;
    #pragma unroll
    for (int it = 0; it < 12; it++) {
        int s = it * 4 + g;
        bool valid = (s < SS);
        float4 kv = *(const float4*)(kb + (size_t)jv[it] * 64 + t * 4);
        float p = qv.x * kv.x + qv.y * kv.y + qv.z * kv.z + qv.w * kv.w;
        p += __shfl_xor(p, 1, 64);
        p += __shfl_xor(p, 2, 64);
        p += __shfl_xor(p, 4, 64);
        p += __shfl_xor(p, 8, 64);
        if (valid) { maxv = fmaxf(maxv, p); sum += p; }
    }
    maxv = fmaxf(maxv, __shfl_xor(maxv, 16, 64));
    maxv = fmaxf(maxv, __shfl_xor(maxv, 32, 64));
    sum += __shfl_xor(sum, 16, 64);
    sum += __shfl_xor(sum, 32, 64);
    if (lane == 0) M[inst] = maxv - sum * (1.f / 45.f);
}

// ---------------- per-(b,h) top-45 of M over L (wave-shuffle reduce) -----------
__global__ __launch_bounds__(256) void topk_kernel(
    const float* __restrict__ M, int* __restrict__ tidx)
{
    int bh = blockIdx.x;
    __shared__ float vals[4096];
    __shared__ float wv[4];
    __shared__ int wi[4];
    int tid = threadIdx.x;
    int lane = tid & 63, w = tid >> 6;
    for (int i = tid; i < 4096; i += 256) vals[i] = M[(size_t)bh * 4096 + i];
    __syncthreads();
    for (int it = 0; it < SS; it++) {
        float bv = -1e38f; int bi = 0x7fffffff;
        for (int i = tid; i < 4096; i += 256) {
            float v = vals[i];
            if (v > bv) { bv = v; bi = i; }
        }
        #pragma unroll
        for (int s = 32; s > 0; s >>= 1) {
            float v2 = __shfl_xor(bv, s, 64);
            int i2 = __shfl_xor(bi, s, 64);
            if (v2 > bv || (v2 == bv && i2 < bi)) { bv = v2; bi = i2; }
        }
        if (lane == 0) { wv[w] = bv; wi[w] = bi; }
        __syncthreads();
        if (tid == 0) {
            float b0 = wv[0]; int i0 = wi[0];
            #pragma unroll
            for (int k = 1; k < 4; k++)
                if (wv[k] > b0 || (wv[k] == b0 && wi[k] < i0)) { b0 = wv[k]; i0 = wi[k]; }
            tidx[bh * SS + it] = i0;
            vals[i0] = -1e38f;
        }
        __syncthreads();
    }
}

// ---------------- v mean partials over l-chunks --------------------------------
__global__ __launch_bounds__(256) void vmean_part_kernel(
    const float* __restrict__ V, float* __restrict__ vmp)
{
    int bh = blockIdx.x;
    int chunk = blockIdx.y;
    int d = threadIdx.x & 63, part = threadIdx.x >> 6;
    const float* vb = V + ((size_t)bh * 4096 + chunk * 256) * 64;
    float s = 0.f;
    for (int l = part; l < 256; l += 4) s += vb[(size_t)l * 64 + d];
    __shared__ float red[4][64];
    red[part][d] = s;
    __syncthreads();
    if (part == 0) vmp[((size_t)bh * 16 + chunk) * 64 + d] = red[0][d] + red[1][d] + red[2][d] + red[3][d];
}

// ---------------- vmean finalize + base_b = mean_row @ Wo ----------------------
__global__ __launch_bounds__(256) void base_kernel(
    const float* __restrict__ vmp, const float* __restrict__ Wo,
    float* __restrict__ vmean, float* __restrict__ base)
{
    int b = blockIdx.x;
    __shared__ float vmS[512];
    int tid = threadIdx.x;
    for (int i = tid; i < 512; i += 256) {
        int h = i >> 6, d = i & 63;
        float s = 0.f;
        #pragma unroll
        for (int c = 0; c < 16; c++) s += vmp[((size_t)(b * 8 + h) * 16 + c) * 64 + d];
        s *= (1.f / 4096.f);
        vmS[i] = s;
        vmean[(size_t)b * 512 + i] = s;
    }
    __syncthreads();
    for (int j = tid; j < 512; j += 256) {
        float s = 0.f;
        for (int i = 0; i < 512; i++) s += vmS[i] * Wo[(size_t)i * 512 + j];
        base[(size_t)b * 512 + j] = s;
    }
}

// ---------------- scores = Qr . k * scale ---------------------------------------
__global__ __launch_bounds__(256) void scores_kernel(
    const float* __restrict__ Q, const float* __restrict__ K,
    const int* __restrict__ tidx, float* __restrict__ attn)
{
    int ltile = blockIdx.x;
    int bh = blockIdx.y;
    __shared__ float Qs[48][68];
    __shared__ float Ks[64][68];
    __shared__ int tS[48];
    int tid = threadIdx.x;
    if (tid < 48) tS[tid] = (tid < SS) ? tidx[bh * SS + tid] : 0;
    __syncthreads();
    int lane = tid & 63, w = tid >> 6;
    for (int u = w; u < 48; u += 4)
        Qs[u][lane] = Q[((size_t)bh * 4096 + tS[u]) * 64 + lane];
    for (int r = w; r < 64; r += 4)
        Ks[r][lane] = K[((size_t)bh * 4096 + ltile * 64 + r) * 64 + lane];
    __syncthreads();
    if (tid < 192) {
        int ug = tid >> 4, lg = tid & 15;
        float acc[4][4];
        #pragma unroll
        for (int i = 0; i < 4; i++)
            #pragma unroll
            for (int j = 0; j < 4; j++) acc[i][j] = 0.f;
        for (int d0 = 0; d0 < 64; d0 += 4) {
            float4 a[4], b[4];
            #pragma unroll
            for (int i = 0; i < 4; i++) a[i] = *(float4*)&Qs[ug * 4 + i][d0];
            #pragma unroll
            for (int j = 0; j < 4; j++) b[j] = *(float4*)&Ks[lg * 4 + j][d0];
            #pragma unroll
            for (int i = 0; i < 4; i++)
                #pragma unroll
                for (int j = 0; j < 4; j++)
                    acc[i][j] += a[i].x * b[j].x + a[i].y * b[j].y + a[i].z * b[j].z + a[i].w * b[j].w;
        }
        const float scale = 0.125f;
        #pragma unroll
        for (int i = 0; i < 4; i++) {
            int u = ug * 4 + i;
            if (u < SS) {
                float4 r = make_float4(acc[i][0] * scale, acc[i][1] * scale,
                                       acc[i][2] * scale, acc[i][3] * scale);
                *(float4*)(attn + (size_t)(bh * SS + u) * 4096 + ltile * 64 + lg * 4) = r;
            }
        }
    }
}

// ---------------- softmax over L per (bh,u) row --------------------------------
__global__ __launch_bounds__(256) void softmax_kernel(float* __restrict__ attn)
{
    int rr = blockIdx.x;
    float* row = attn + (size_t)rr * 4096;
    int tid = threadIdx.x;
    float v[16];
    float m = -1e30f;
    #pragma unroll
    for (int i = 0; i < 16; i++) { v[i] = row[tid + 256 * i]; m = fmaxf(m, v[i]); }
    __shared__ float red[256];
    red[tid] = m; __syncthreads();
    for (int s = 128; s > 0; s >>= 1) { if (tid < s) red[tid] = fmaxf(red[tid], red[tid + s]); __syncthreads(); }
    m = red[0]; __syncthreads();
    float sum = 0.f;
    #pragma unroll
    for (int i = 0; i < 16; i++) { v[i] = __expf(v[i] - m); sum += v[i]; }
    red[tid] = sum; __syncthreads();
    for (int s = 128; s > 0; s >>= 1) { if (tid < s) red[tid] += red[tid + s]; __syncthreads(); }
    float inv = 1.f / red[0];
    #pragma unroll
    for (int i = 0; i < 16; i++) row[tid + 256 * i] = v[i] * inv;
}

// ---------------- PV partials ---------------------------------------------------
__global__ __launch_bounds__(256) void pv_kernel(
    const float* __restrict__ attn, const float* __restrict__ V,
    float* __restrict__ part)
{
    int bh = blockIdx.x;
    int ks = blockIdx.y;
    int tid = threadIdx.x;
    int d = tid & 63, w = tid >> 6;
    float acc[12];
    #pragma unroll
    for (int j = 0; j < 12; j++) acc[j] = 0.f;
    const float* vb = V + ((size_t)bh * 4096 + ks * 256) * 64;
    for (int li = 0; li < 256; li++) {
        float vv = vb[(size_t)li * 64 + d];
        #pragma unroll
        for (int j = 0; j < 12; j++) {
            int u = w + 4 * j;
            float a = (u < SS) ? attn[(size_t)(bh * SS + u) * 4096 + ks * 256 + li] : 0.f;
            acc[j] += a * vv;
        }
    }
    #pragma unroll
    for (int j = 0; j < 12; j++) {
        int u = w + 4 * j;
        if (u < SS) part[(((size_t)bh * 16 + ks) * SS + u) * 64 + d] = acc[j];
    }
}

// ---------------- delta_out[bh,u,:] = (ctx_sel - vmean) @ Wo_h ------------------
__global__ __launch_bounds__(256) void delta_kernel(
    const float* __restrict__ part, const float* __restrict__ vmean,
    const float* __restrict__ Wo, float* __restrict__ dout)
{
    int rr = blockIdx.x;
    int bh = rr / SS, u = rr % SS;
    int h = bh & 7;
    __shared__ float dS[64];
    int tid = threadIdx.x;
    if (tid < 64) {
        float s = 0.f;
        #pragma unroll
        for (int c = 0; c < 16; c++) s += part[(((size_t)bh * 16 + c) * SS + u) * 64 + tid];
        dS[tid] = s - vmean[(size_t)bh * 64 + tid];
    }
    __syncthreads();
    for (int j = tid; j < 512; j += 256) {
        float s = 0.f;
        #pragma unroll
        for (int dd = 0; dd < 64; dd++) s += dS[dd] * Wo[(size_t)(h * 64 + dd) * 512 + j];
        dout[(size_t)rr * 512 + j] = s;
    }
}

// ---------------- fill out with per-b base row ---------------------------------
__global__ __launch_bounds__(256) void fill_kernel(
    const float4* __restrict__ base4, float4* __restrict__ out4)
{
    int i = blockIdx.x * 256 + threadIdx.x;
    int b = i >> 19;
    int j4 = i & 127;
    out4[i] = base4[b * 128 + j4];
}

// ---------------- scatter-add deltas into selected rows -------------------------
__global__ __launch_bounds__(256) void scatter_kernel(
    const float* __restrict__ dout, const int* __restrict__ tidx,
    float* __restrict__ out)
{
    int rr = blockIdx.x;
    int bh = rr / SS;
    int b = bh >> 3;
    int l = tidx[rr];
    float* orow = out + ((size_t)b * 4096 + l) * 512;
    const float* drow = dout + (size_t)rr * 512;
    for (int j = threadIdx.x; j < 512; j += 256)
        atomicAdd(orow + j, drow[j]);
}

extern "C" void kernel_launch(void* const* d_in, const int* in_sizes, int n_in,
                              void* d_out, int out_size, void* d_ws, size_t ws_size,
                              hipStream_t stream)
{
    const float* x  = (const float*)d_in[0];
    const float* Wq = (const float*)d_in[1];
    const float* Wk = (const float*)d_in[2];
    const float* Wv = (const float*)d_in[3];
    const float* Wo = (const float*)d_in[4];
    const int*  idx = (const int*)d_in[5];
    float* out = (float*)d_out;

    float* W = (float*)d_ws;
    float* Q = W;                        // 8,388,608 f
    float* K = W + 8388608;              // 8,388,608 f
    float* V = W + 16777216;             // 8,388,608 f
    // x hi/lo planes (u16): live convx2 -> qk2/vgemm only
    unsigned short* xh = (unsigned short*)(W + 25165824);   // 8,388,608 u16
    unsigned short* xl = (unsigned short*)(W + 29360128);   // 8,388,608 u16
    unsigned short* WTh = (unsigned short*)(W + 33554432);  // 786,432 u16
    unsigned short* WTl = (unsigned short*)(W + 33947648);  // 786,432 u16
    // total: 34,340,864 floats = 137.4 MB

    // post-projection buffers alias the xh/xl region (all written only after
    // vgemm has consumed xh; stream order serializes)
    float* Mv    = W + 25165824;         // 131,072
    float* attn  = W + 25296896;         // 5,898,240
    float* part  = W + 31195136;         // 1,474,560
    float* dout  = W + 32669696;         // 737,280
    float* vmp   = W + 33406976;         // 32,768
    float* vmean = W + 33439744;         // 2,048
    float* base  = W + 33441792;         // 2,048
    int*   tidx  = (int*)(W + 33443840); // 1,440 ints  (ends 33,445,280 < 33,554,432)

    convx2_kernel<<<8192, 256, 0, stream>>>((const float4*)x, (ushort4*)xh, (ushort4*)xl);
    convw2_kernel<<<dim3(256, 3), 256, 0, stream>>>(Wq, Wk, Wv, WTh, WTl);
    qk2_kernel<<<dim3(128, 8), 256, 0, stream>>>(xh, xl, WTh, WTl, Q, K);
    vgemm_kernel<<<dim3(128, 8), 256, 0, stream>>>(xh, WTh + (size_t)2 * 512 * 512, V);
    m_kernel<<<32768, 256, 0, stream>>>(Q, K, idx, Mv);
    topk_kernel<<<32, 256, 0, stream>>>(Mv, tidx);
    vmean_part_kernel<<<dim3(32, 16), 256, 0, stream>>>(V, vmp);
    base_kernel<<<4, 256, 0, stream>>>(vmp, Wo, vmean, base);
    scores_kernel<<<dim3(64, 32), 256, 0, stream>>>(Q, K, tidx, attn);
    softmax_kernel<<<1440, 256, 0, stream>>>(attn);
    pv_kernel<<<dim3(32, 16), 256, 0, stream>>>(attn, V, part);
    delta_kernel<<<1440, 256, 0, stream>>>(part, vmean, Wo, dout);
    fill_kernel<<<8192, 256, 0, stream>>>((const float4*)base, (float4*)out);
    scatter_kernel<<<1440, 256, 0, stream>>>(dout, tidx, out);
}

// Round 6
// 597.500 us; speedup vs baseline: 1.1109x; 1.1109x over previous
//
#include <hip/hip_runtime.h>
#include <cmath>

#define SS 45

typedef __attribute__((ext_vector_type(8))) _Float16 half8;
typedef __attribute__((ext_vector_type(4))) float float4v;

__device__ inline unsigned short f16b(float f) {
    union { _Float16 h; unsigned short u; } c;
    c.h = (_Float16)f;
    return c.u;
}
__device__ inline float f16back(unsigned short u) {
    union { _Float16 h; unsigned short u; } c;
    c.u = u;
    return (float)c.h;
}

// ---- x -> xh (fp16 RTN) + xl (fp16 of residual) -------------------------------
__global__ __launch_bounds__(256) void convx2_kernel(
    const float4* __restrict__ x4, ushort4* __restrict__ xh4, ushort4* __restrict__ xl4)
{
    int i = blockIdx.x * 256 + threadIdx.x;   // 2,097,152
    float4 v = x4[i];
    float fv[4] = {v.x, v.y, v.z, v.w};
    ushort4 h, l;
    unsigned short hh[4], ll[4];
    #pragma unroll
    for (int e = 0; e < 4; e++) {
        hh[e] = f16b(fv[e]);
        ll[e] = f16b(fv[e] - f16back(hh[e]));
    }
    h.x = hh[0]; h.y = hh[1]; h.z = hh[2]; h.w = hh[3];
    l.x = ll[0]; l.y = ll[1]; l.z = ll[2]; l.w = ll[3];
    xh4[i] = h; xl4[i] = l;
}

// ---- Wq/Wk/Wv -> transposed fp16 hi/lo: WT[z][n][k] ---------------------------
__global__ __launch_bounds__(256) void convw2_kernel(
    const float* __restrict__ Wq, const float* __restrict__ Wk, const float* __restrict__ Wv,
    unsigned short* __restrict__ WTh, unsigned short* __restrict__ WTl)
{
    const float* W = (blockIdx.y == 0) ? Wq : (blockIdx.y == 1) ? Wk : Wv;
    unsigned short* th = WTh + (size_t)blockIdx.y * 512 * 512;
    unsigned short* tl = WTl + (size_t)blockIdx.y * 512 * 512;
    __shared__ float t[32][33];
    int bx = blockIdx.x & 15, by = blockIdx.x >> 4;
    int tx = threadIdx.x & 31, ty = threadIdx.x >> 5;
    for (int i = ty; i < 32; i += 8) t[i][tx] = W[(size_t)(by * 32 + i) * 512 + bx * 32 + tx];
    __syncthreads();
    for (int i = ty; i < 32; i += 8) {
        float f = t[tx][i];   // W[k = by*32+tx][n = bx*32+i]
        unsigned short h = f16b(f);
        unsigned short lo = f16b(f - f16back(h));
        th[(size_t)(bx * 32 + i) * 512 + by * 32 + tx] = h;
        tl[(size_t)(bx * 32 + i) * 512 + by * 32 + tx] = lo;
    }
}

// ---- fused Q,K projection, split-fp16 MFMA (hh+hl+lh), full-head writes -------
// grid (128, 4); block 128m x 128n; wave 64m x 64n (one full head per wave).
__global__ __launch_bounds__(256, 2) void qk3_kernel(
    const unsigned short* __restrict__ Xh, const unsigned short* __restrict__ Xl,
    const unsigned short* __restrict__ WTh, const unsigned short* __restrict__ WTl,
    float* __restrict__ Q, float* __restrict__ K)
{
    int wave = threadIdx.x >> 6;
    int lane = threadIdx.x & 63;
    int m0 = blockIdx.x * 128 + (wave >> 1) * 64;
    int n0 = blockIdx.y * 128 + (wave & 1) * 64;
    int fr = lane & 15;
    int kq = (lane >> 4) * 8;
    const unsigned short* Bqh = WTh;
    const unsigned short* Bql = WTl;
    const unsigned short* Bkh = WTh + 512 * 512;
    const unsigned short* Bkl = WTl + 512 * 512;

    float4v accq[4][4], acck[4][4];
    #pragma unroll
    for (int i = 0; i < 4; i++)
        #pragma unroll
        for (int j = 0; j < 4; j++) {
            accq[i][j] = (float4v){0.f, 0.f, 0.f, 0.f};
            acck[i][j] = (float4v){0.f, 0.f, 0.f, 0.f};
        }

    for (int k0 = 0; k0 < 512; k0 += 32) {
        half8 ah[4], al[4];
        #pragma unroll
        for (int i = 0; i < 4; i++) {
            size_t aoff = (size_t)(m0 + i * 16 + fr) * 512 + k0 + kq;
            ah[i] = *(const half8*)(Xh + aoff);
            al[i] = *(const half8*)(Xl + aoff);
        }
        #pragma unroll
        for (int j = 0; j < 4; j++) {
            size_t boff = (size_t)(n0 + j * 16 + fr) * 512 + k0 + kq;
            half8 bqh = *(const half8*)(Bqh + boff);
            half8 bql = *(const half8*)(Bql + boff);
            half8 bkh = *(const half8*)(Bkh + boff);
            half8 bkl = *(const half8*)(Bkl + boff);
            #pragma unroll
            for (int i = 0; i < 4; i++) {
                accq[i][j] = __builtin_amdgcn_mfma_f32_16x16x32_f16(ah[i], bqh, accq[i][j], 0, 0, 0);
                accq[i][j] = __builtin_amdgcn_mfma_f32_16x16x32_f16(ah[i], bql, accq[i][j], 0, 0, 0);
                accq[i][j] = __builtin_amdgcn_mfma_f32_16x16x32_f16(al[i], bqh, accq[i][j], 0, 0, 0);
                acck[i][j] = __builtin_amdgcn_mfma_f32_16x16x32_f16(ah[i], bkh, acck[i][j], 0, 0, 0);
                acck[i][j] = __builtin_amdgcn_mfma_f32_16x16x32_f16(ah[i], bkl, acck[i][j], 0, 0, 0);
                acck[i][j] = __builtin_amdgcn_mfma_f32_16x16x32_f16(al[i], bkh, acck[i][j], 0, 0, 0);
            }
        }
    }
    // C/D layout: col = lane&15, row = (lane>>4)*4 + reg
    int rbase = (lane >> 4) * 4, ccol = lane & 15;
    #pragma unroll
    for (int i = 0; i < 4; i++)
        #pragma unroll
        for (int j = 0; j < 4; j++) {
            int c = n0 + j * 16 + ccol;
            int h = c >> 6, d = c & 63;
            #pragma unroll
            for (int r = 0; r < 4; r++) {
                int rg = m0 + i * 16 + rbase + r;
                int bb = rg >> 12, l = rg & 4095;
                size_t off = ((size_t)(bb * 8 + h) * 4096 + l) * 64 + d;
                Q[off] = accq[i][j][r];
                K[off] = acck[i][j][r];
            }
        }
}

// ---- V GEMM via fp16 MFMA (hi plane only), full-head writes -------------------
__global__ __launch_bounds__(256, 3) void vgemm_kernel(
    const unsigned short* __restrict__ Xh,
    const unsigned short* __restrict__ BTh,   // WT z=2 (hi)
    float* __restrict__ V)
{
    int wave = threadIdx.x >> 6;
    int lane = threadIdx.x & 63;
    int m0 = blockIdx.x * 128 + (wave >> 1) * 64;
    int n0 = blockIdx.y * 128 + (wave & 1) * 64;
    int fr = lane & 15;
    int kq = (lane >> 4) * 8;

    float4v acc[4][4];
    #pragma unroll
    for (int i = 0; i < 4; i++)
        #pragma unroll
        for (int j = 0; j < 4; j++) acc[i][j] = (float4v){0.f, 0.f, 0.f, 0.f};

    for (int k0 = 0; k0 < 512; k0 += 32) {
        half8 a[4], b[4];
        #pragma unroll
        for (int i = 0; i < 4; i++)
            a[i] = *(const half8*)(Xh + (size_t)(m0 + i * 16 + fr) * 512 + k0 + kq);
        #pragma unroll
        for (int j = 0; j < 4; j++)
            b[j] = *(const half8*)(BTh + (size_t)(n0 + j * 16 + fr) * 512 + k0 + kq);
        #pragma unroll
        for (int i = 0; i < 4; i++)
            #pragma unroll
            for (int j = 0; j < 4; j++)
                acc[i][j] = __builtin_amdgcn_mfma_f32_16x16x32_f16(a[i], b[j], acc[i][j], 0, 0, 0);
    }
    int rbase = (lane >> 4) * 4, ccol = lane & 15;
    #pragma unroll
    for (int i = 0; i < 4; i++)
        #pragma unroll
        for (int j = 0; j < 4; j++) {
            int c = n0 + j * 16 + ccol;
            int h = c >> 6, d = c & 63;
            #pragma unroll
            for (int r = 0; r < 4; r++) {
                int rg = m0 + i * 16 + rbase + r;
                int bb = rg >> 12, l = rg & 4095;
                V[((size_t)(bb * 8 + h) * 4096 + l) * 64 + d] = acc[i][j][r];
            }
        }
}

// ---------------- M = max_s(q.k_samp) - mean_s(q.k_samp), fp32 ----------------
__global__ __launch_bounds__(256) void m_kernel(
    const float* __restrict__ Q, const float* __restrict__ K,
    const int* __restrict__ idx, float* __restrict__ M)
{
    int inst = blockIdx.x * 4 + (threadIdx.x >> 6);   // bh*4096 + l
    int lane = threadIdx.x & 63;
    int g = lane >> 4;
    int t = lane & 15;
    int bh = inst >> 12;
    int l = inst & 4095;
    float4 qv = *(const float4*)(Q + (size_t)inst * 64 + t * 4);
    const float* kb = K + (size_t)bh * 4096 * 64;
    const int* irow = idx + (size_t)l * SS;
    int jv[12];
    #pragma unroll
    for (int it = 0; it < 12; it++) {
        int s = it * 4 + g;
        jv[it] = irow[(s < SS) ? s : 0];
    }
    float maxv = -1e30f, sum = 0.f;
    #pragma unroll
    for (int it = 0; it < 12; it++) {
        int s = it * 4 + g;
        bool valid = (s < SS);
        float4 kv = *(const float4*)(kb + (size_t)jv[it] * 64 + t * 4);
        float p = qv.x * kv.x + qv.y * kv.y + qv.z * kv.z + qv.w * kv.w;
        p += __shfl_xor(p, 1, 64);
        p += __shfl_xor(p, 2, 64);
        p += __shfl_xor(p, 4, 64);
        p += __shfl_xor(p, 8, 64);
        if (valid) { maxv = fmaxf(maxv, p); sum += p; }
    }
    maxv = fmaxf(maxv, __shfl_xor(maxv, 16, 64));
    maxv = fmaxf(maxv, __shfl_xor(maxv, 32, 64));
    sum += __shfl_xor(sum, 16, 64);
    sum += __shfl_xor(sum, 32, 64);
    if (lane == 0) M[inst] = maxv - sum * (1.f / 45.f);
}

// ---------------- per-(b,h) top-45 of M over L (wave-shuffle reduce) -----------
__global__ __launch_bounds__(256) void topk_kernel(
    const float* __restrict__ M, int* __restrict__ tidx)
{
    int bh = blockIdx.x;
    __shared__ float vals[4096];
    __shared__ float wv[4];
    __shared__ int wi[4];
    int tid = threadIdx.x;
    int lane = tid & 63, w = tid >> 6;
    for (int i = tid; i < 4096; i += 256) vals[i] = M[(size_t)bh * 4096 + i];
    __syncthreads();
    for (int it = 0; it < SS; it++) {
        float bv = -1e38f; int bi = 0x7fffffff;
        for (int i = tid; i < 4096; i += 256) {
            float v = vals[i];
            if (v > bv) { bv = v; bi = i; }
        }
        #pragma unroll
        for (int s = 32; s > 0; s >>= 1) {
            float v2 = __shfl_xor(bv, s, 64);
            int i2 = __shfl_xor(bi, s, 64);
            if (v2 > bv || (v2 == bv && i2 < bi)) { bv = v2; bi = i2; }
        }
        if (lane == 0) { wv[w] = bv; wi[w] = bi; }
        __syncthreads();
        if (tid == 0) {
            float b0 = wv[0]; int i0 = wi[0];
            #pragma unroll
            for (int k = 1; k < 4; k++)
                if (wv[k] > b0 || (wv[k] == b0 && wi[k] < i0)) { b0 = wv[k]; i0 = wi[k]; }
            tidx[bh * SS + it] = i0;
            vals[i0] = -1e38f;
        }
        __syncthreads();
    }
}

// ---------------- v mean partials over l-chunks --------------------------------
__global__ __launch_bounds__(256) void vmean_part_kernel(
    const float* __restrict__ V, float* __restrict__ vmp)
{
    int bh = blockIdx.x;
    int chunk = blockIdx.y;
    int d = threadIdx.x & 63, part = threadIdx.x >> 6;
    const float* vb = V + ((size_t)bh * 4096 + chunk * 256) * 64;
    float s = 0.f;
    for (int l = part; l < 256; l += 4) s += vb[(size_t)l * 64 + d];
    __shared__ float red[4][64];
    red[part][d] = s;
    __syncthreads();
    if (part == 0) vmp[((size_t)bh * 16 + chunk) * 64 + d] = red[0][d] + red[1][d] + red[2][d] + red[3][d];
}

// ---------------- vmean finalize + base_b = mean_row @ Wo ----------------------
__global__ __launch_bounds__(256) void base_kernel(
    const float* __restrict__ vmp, const float* __restrict__ Wo,
    float* __restrict__ vmean, float* __restrict__ base)
{
    int b = blockIdx.x;
    __shared__ float vmS[512];
    int tid = threadIdx.x;
    for (int i = tid; i < 512; i += 256) {
        int h = i >> 6, d = i & 63;
        float s = 0.f;
        #pragma unroll
        for (int c = 0; c < 16; c++) s += vmp[((size_t)(b * 8 + h) * 16 + c) * 64 + d];
        s *= (1.f / 4096.f);
        vmS[i] = s;
        vmean[(size_t)b * 512 + i] = s;
    }
    __syncthreads();
    for (int j = tid; j < 512; j += 256) {
        float s = 0.f;
        for (int i = 0; i < 512; i++) s += vmS[i] * Wo[(size_t)i * 512 + j];
        base[(size_t)b * 512 + j] = s;
    }
}

// ---------------- zero ctx accumulator -----------------------------------------
__global__ __launch_bounds__(256) void zeroctx_kernel(float* __restrict__ ctx)
{
    ctx[blockIdx.x * 256 + threadIdx.x] = 0.f;   // grid 360 -> 92,160
}

// ---------------- scores = Qr . k * scale ---------------------------------------
__global__ __launch_bounds__(256) void scores_kernel(
    const float* __restrict__ Q, const float* __restrict__ K,
    const int* __restrict__ tidx, float* __restrict__ attn)
{
    int ltile = blockIdx.x;
    int bh = blockIdx.y;
    __shared__ float Qs[48][68];
    __shared__ float Ks[64][68];
    __shared__ int tS[48];
    int tid = threadIdx.x;
    if (tid < 48) tS[tid] = (tid < SS) ? tidx[bh * SS + tid] : 0;
    __syncthreads();
    int lane = tid & 63, w = tid >> 6;
    for (int u = w; u < 48; u += 4)
        Qs[u][lane] = Q[((size_t)bh * 4096 + tS[u]) * 64 + lane];
    for (int r = w; r < 64; r += 4)
        Ks[r][lane] = K[((size_t)bh * 4096 + ltile * 64 + r) * 64 + lane];
    __syncthreads();
    if (tid < 192) {
        int ug = tid >> 4, lg = tid & 15;
        float acc[4][4];
        #pragma unroll
        for (int i = 0; i < 4; i++)
            #pragma unroll
            for (int j = 0; j < 4; j++) acc[i][j] = 0.f;
        for (int d0 = 0; d0 < 64; d0 += 4) {
            float4 a[4], b[4];
            #pragma unroll
            for (int i = 0; i < 4; i++) a[i] = *(float4*)&Qs[ug * 4 + i][d0];
            #pragma unroll
            for (int j = 0; j < 4; j++) b[j] = *(float4*)&Ks[lg * 4 + j][d0];
            #pragma unroll
            for (int i = 0; i < 4; i++)
                #pragma unroll
                for (int j = 0; j < 4; j++)
                    acc[i][j] += a[i].x * b[j].x + a[i].y * b[j].y + a[i].z * b[j].z + a[i].w * b[j].w;
        }
        const float scale = 0.125f;
        #pragma unroll
        for (int i = 0; i < 4; i++) {
            int u = ug * 4 + i;
            if (u < SS) {
                float4 r = make_float4(acc[i][0] * scale, acc[i][1] * scale,
                                       acc[i][2] * scale, acc[i][3] * scale);
                *(float4*)(attn + (size_t)(bh * SS + u) * 4096 + ltile * 64 + lg * 4) = r;
            }
        }
    }
}

// ---------------- softmax over L per (bh,u) row --------------------------------
__global__ __launch_bounds__(256) void softmax_kernel(float* __restrict__ attn)
{
    int rr = blockIdx.x;
    float* row = attn + (size_t)rr * 4096;
    int tid = threadIdx.x;
    float v[16];
    float m = -1e30f;
    #pragma unroll
    for (int i = 0; i < 16; i++) { v[i] = row[tid + 256 * i]; m = fmaxf(m, v[i]); }
    __shared__ float red[256];
    red[tid] = m; __syncthreads();
    for (int s = 128; s > 0; s >>= 1) { if (tid < s) red[tid] = fmaxf(red[tid], red[tid + s]); __syncthreads(); }
    m = red[0]; __syncthreads();
    float sum = 0.f;
    #pragma unroll
    for (int i = 0; i < 16; i++) { v[i] = __expf(v[i] - m); sum += v[i]; }
    red[tid] = sum; __syncthreads();
    for (int s = 128; s > 0; s >>= 1) { if (tid < s) red[tid] += red[tid + s]; __syncthreads(); }
    float inv = 1.f / red[0];
    #pragma unroll
    for (int i = 0; i < 16; i++) row[tid + 256 * i] = v[i] * inv;
}

// ---------------- PV: partial over 64-l chunk, atomicAdd into ctx ---------------
__global__ __launch_bounds__(256) void pv_kernel(
    const float* __restrict__ attn, const float* __restrict__ V,
    float* __restrict__ ctx)
{
    int bh = blockIdx.x;   // 32
    int ck = blockIdx.y;   // 64 chunks of 64 l
    int tid = threadIdx.x;
    int d = tid & 63, w = tid >> 6;
    float acc[12];
    #pragma unroll
    for (int j = 0; j < 12; j++) acc[j] = 0.f;
    const float* vb = V + ((size_t)bh * 4096 + ck * 64) * 64;
    const float* ab = attn + (size_t)bh * SS * 4096 + ck * 64;
    for (int li = 0; li < 64; li++) {
        float vv = vb[(size_t)li * 64 + d];
        #pragma unroll
        for (int j = 0; j < 12; j++) {
            int u = w + 4 * j;
            float a = (u < SS) ? ab[(size_t)u * 4096 + li] : 0.f;
            acc[j] += a * vv;
        }
    }
    #pragma unroll
    for (int j = 0; j < 12; j++) {
        int u = w + 4 * j;
        if (u < SS) atomicAdd(ctx + ((size_t)bh * SS + u) * 64 + d, acc[j]);
    }
}

// ---------------- delta_out[bh,u,:] = (ctx - vmean) @ Wo_h ----------------------
__global__ __launch_bounds__(256) void delta_kernel(
    const float* __restrict__ ctx, const float* __restrict__ vmean,
    const float* __restrict__ Wo, float* __restrict__ dout)
{
    int rr = blockIdx.x;          // bh*45 + u
    int bh = rr / SS;
    int h = bh & 7;
    __shared__ float dS[64];
    int tid = threadIdx.x;
    if (tid < 64)
        dS[tid] = ctx[(size_t)rr * 64 + tid] - vmean[(size_t)bh * 64 + tid];
    __syncthreads();
    for (int j = tid; j < 512; j += 256) {
        float s = 0.f;
        #pragma unroll
        for (int dd = 0; dd < 64; dd++) s += dS[dd] * Wo[(size_t)(h * 64 + dd) * 512 + j];
        dout[(size_t)rr * 512 + j] = s;
    }
}

// ---------------- fill out with per-b base row ---------------------------------
__global__ __launch_bounds__(256) void fill_kernel(
    const float4* __restrict__ base4, float4* __restrict__ out4)
{
    int i = blockIdx.x * 256 + threadIdx.x;
    int b = i >> 19;
    int j4 = i & 127;
    out4[i] = base4[b * 128 + j4];
}

// ---------------- scatter-add deltas into selected rows -------------------------
__global__ __launch_bounds__(256) void scatter_kernel(
    const float* __restrict__ dout, const int* __restrict__ tidx,
    float* __restrict__ out)
{
    int rr = blockIdx.x;
    int bh = rr / SS;
    int b = bh >> 3;
    int l = tidx[rr];
    float* orow = out + ((size_t)b * 4096 + l) * 512;
    const float* drow = dout + (size_t)rr * 512;
    for (int j = threadIdx.x; j < 512; j += 256)
        atomicAdd(orow + j, drow[j]);
}

extern "C" void kernel_launch(void* const* d_in, const int* in_sizes, int n_in,
                              void* d_out, int out_size, void* d_ws, size_t ws_size,
                              hipStream_t stream)
{
    const float* x  = (const float*)d_in[0];
    const float* Wq = (const float*)d_in[1];
    const float* Wk = (const float*)d_in[2];
    const float* Wv = (const float*)d_in[3];
    const float* Wo = (const float*)d_in[4];
    const int*  idx = (const int*)d_in[5];
    float* out = (float*)d_out;

    float* W = (float*)d_ws;
    float* Q = W;                        // 8,388,608 f
    float* K = W + 8388608;              // 8,388,608 f
    float* V = W + 16777216;             // 8,388,608 f
    // fp16 staging (live: conv -> qk3/vgemm only)
    unsigned short* xh  = (unsigned short*)(W + 25165824);  // 8,388,608 u16 -> ends 29360128
    unsigned short* xl  = (unsigned short*)(W + 29360128);  // 8,388,608 u16 -> ends 33554432
    unsigned short* WTh = (unsigned short*)(W + 33554432);  // 786,432 u16  -> ends 33947648
    unsigned short* WTl = (unsigned short*)(W + 33947648);  // 786,432 u16  -> ends 34340864
    // total 137.4 MB (same as R5, proven)

    // post-projection buffers alias xh/xl (all written after vgemm/qk3 consume them)
    float* Mv    = W + 25165824;         // 131,072
    float* attn  = W + 25296896;         // 5,898,240 -> ends 31195136
    float* ctx   = W + 31195136;         // 92,160    -> ends 31287296
    float* dout  = W + 32669696;         // 737,280   -> ends 33406976
    float* vmp   = W + 33406976;         // 32,768
    float* vmean = W + 33439744;         // 2,048
    float* base  = W + 33441792;         // 2,048
    int*   tidx  = (int*)(W + 33443840); // 1,440 ints (ends 33,445,280 < 33,554,432)

    convx2_kernel<<<8192, 256, 0, stream>>>((const float4*)x, (ushort4*)xh, (ushort4*)xl);
    convw2_kernel<<<dim3(256, 3), 256, 0, stream>>>(Wq, Wk, Wv, WTh, WTl);
    qk3_kernel<<<dim3(128, 4), 256, 0, stream>>>(xh, xl, WTh, WTl, Q, K);
    vgemm_kernel<<<dim3(128, 4), 256, 0, stream>>>(xh, WTh + (size_t)2 * 512 * 512, V);
    m_kernel<<<32768, 256, 0, stream>>>(Q, K, idx, Mv);
    topk_kernel<<<32, 256, 0, stream>>>(Mv, tidx);
    vmean_part_kernel<<<dim3(32, 16), 256, 0, stream>>>(V, vmp);
    base_kernel<<<4, 256, 0, stream>>>(vmp, Wo, vmean, base);
    zeroctx_kernel<<<360, 256, 0, stream>>>(ctx);
    scores_kernel<<<dim3(64, 32), 256, 0, stream>>>(Q, K, tidx, attn);
    softmax_kernel<<<1440, 256, 0, stream>>>(attn);
    pv_kernel<<<dim3(32, 64), 256, 0, stream>>>(attn, V, ctx);
    delta_kernel<<<1440, 256, 0, stream>>>(ctx, vmean, Wo, dout);
    fill_kernel<<<8192, 256, 0, stream>>>((const float4*)base, (float4*)out);
    scatter_kernel<<<1440, 256, 0, stream>>>(dout, tidx, out);
}

// Round 7
// 595.470 us; speedup vs baseline: 1.1147x; 1.0034x over previous
//
#include <hip/hip_runtime.h>
#include <cmath>

#define SS 45

typedef __attribute__((ext_vector_type(8))) _Float16 half8;
typedef __attribute__((ext_vector_type(4))) float float4v;

__device__ inline unsigned short f16b(float f) {
    union { _Float16 h; unsigned short u; } c;
    c.h = (_Float16)f;
    return c.u;
}
__device__ inline float f16back(unsigned short u) {
    union { _Float16 h; unsigned short u; } c;
    c.u = u;
    return (float)c.h;
}

// ---- x -> xh (fp16 RTN) + xl (fp16 of residual) -------------------------------
__global__ __launch_bounds__(256) void convx2_kernel(
    const float4* __restrict__ x4, ushort4* __restrict__ xh4, ushort4* __restrict__ xl4)
{
    int i = blockIdx.x * 256 + threadIdx.x;   // 2,097,152
    float4 v = x4[i];
    float fv[4] = {v.x, v.y, v.z, v.w};
    ushort4 h, l;
    unsigned short hh[4], ll[4];
    #pragma unroll
    for (int e = 0; e < 4; e++) {
        hh[e] = f16b(fv[e]);
        ll[e] = f16b(fv[e] - f16back(hh[e]));
    }
    h.x = hh[0]; h.y = hh[1]; h.z = hh[2]; h.w = hh[3];
    l.x = ll[0]; l.y = ll[1]; l.z = ll[2]; l.w = ll[3];
    xh4[i] = h; xl4[i] = l;
}

// ---- Wq/Wk/Wv -> transposed fp16 hi/lo: WT[z][n][k] ---------------------------
__global__ __launch_bounds__(256) void convw2_kernel(
    const float* __restrict__ Wq, const float* __restrict__ Wk, const float* __restrict__ Wv,
    unsigned short* __restrict__ WTh, unsigned short* __restrict__ WTl)
{
    const float* W = (blockIdx.y == 0) ? Wq : (blockIdx.y == 1) ? Wk : Wv;
    unsigned short* th = WTh + (size_t)blockIdx.y * 512 * 512;
    unsigned short* tl = WTl + (size_t)blockIdx.y * 512 * 512;
    __shared__ float t[32][33];
    int bx = blockIdx.x & 15, by = blockIdx.x >> 4;
    int tx = threadIdx.x & 31, ty = threadIdx.x >> 5;
    for (int i = ty; i < 32; i += 8) t[i][tx] = W[(size_t)(by * 32 + i) * 512 + bx * 32 + tx];
    __syncthreads();
    for (int i = ty; i < 32; i += 8) {
        float f = t[tx][i];   // W[k = by*32+tx][n = bx*32+i]
        unsigned short h = f16b(f);
        unsigned short lo = f16b(f - f16back(h));
        th[(size_t)(bx * 32 + i) * 512 + by * 32 + tx] = h;
        tl[(size_t)(bx * 32 + i) * 512 + by * 32 + tx] = lo;
    }
}

// ---- fused Q,K projection, split-fp16 MFMA (hh+hl+lh), hoisted loads ----------
// grid (128, 4); block 128m x 128n; wave 64m x 64n (one full head per wave).
__global__ __launch_bounds__(256, 2) void qk3_kernel(
    const unsigned short* __restrict__ Xh, const unsigned short* __restrict__ Xl,
    const unsigned short* __restrict__ WTh, const unsigned short* __restrict__ WTl,
    float* __restrict__ Q, float* __restrict__ K)
{
    int wave = threadIdx.x >> 6;
    int lane = threadIdx.x & 63;
    int m0 = blockIdx.x * 128 + (wave >> 1) * 64;
    int n0 = blockIdx.y * 128 + (wave & 1) * 64;
    int fr = lane & 15;
    int kq = (lane >> 4) * 8;
    const unsigned short* Bqh = WTh;
    const unsigned short* Bql = WTl;
    const unsigned short* Bkh = WTh + 512 * 512;
    const unsigned short* Bkl = WTl + 512 * 512;

    float4v accq[4][4], acck[4][4];
    #pragma unroll
    for (int i = 0; i < 4; i++)
        #pragma unroll
        for (int j = 0; j < 4; j++) {
            accq[i][j] = (float4v){0.f, 0.f, 0.f, 0.f};
            acck[i][j] = (float4v){0.f, 0.f, 0.f, 0.f};
        }

    for (int k0 = 0; k0 < 512; k0 += 32) {
        // ---- hoist A loads (8 independent) ----
        half8 ah[4], al[4];
        #pragma unroll
        for (int i = 0; i < 4; i++) {
            size_t aoff = (size_t)(m0 + i * 16 + fr) * 512 + k0 + kq;
            ah[i] = *(const half8*)(Xh + aoff);
            al[i] = *(const half8*)(Xl + aoff);
        }
        // ---- hoist all 8 Q-weight frags, then 48 q-MFMAs ----
        half8 bqh[4], bql[4];
        #pragma unroll
        for (int j = 0; j < 4; j++) {
            size_t boff = (size_t)(n0 + j * 16 + fr) * 512 + k0 + kq;
            bqh[j] = *(const half8*)(Bqh + boff);
            bql[j] = *(const half8*)(Bql + boff);
        }
        #pragma unroll
        for (int j = 0; j < 4; j++)
            #pragma unroll
            for (int i = 0; i < 4; i++) {
                accq[i][j] = __builtin_amdgcn_mfma_f32_16x16x32_f16(ah[i], bqh[j], accq[i][j], 0, 0, 0);
                accq[i][j] = __builtin_amdgcn_mfma_f32_16x16x32_f16(ah[i], bql[j], accq[i][j], 0, 0, 0);
                accq[i][j] = __builtin_amdgcn_mfma_f32_16x16x32_f16(al[i], bqh[j], accq[i][j], 0, 0, 0);
            }
        // ---- hoist all 8 K-weight frags, then 48 k-MFMAs ----
        half8 bkh[4], bkl[4];
        #pragma unroll
        for (int j = 0; j < 4; j++) {
            size_t boff = (size_t)(n0 + j * 16 + fr) * 512 + k0 + kq;
            bkh[j] = *(const half8*)(Bkh + boff);
            bkl[j] = *(const half8*)(Bkl + boff);
        }
        #pragma unroll
        for (int j = 0; j < 4; j++)
            #pragma unroll
            for (int i = 0; i < 4; i++) {
                acck[i][j] = __builtin_amdgcn_mfma_f32_16x16x32_f16(ah[i], bkh[j], acck[i][j], 0, 0, 0);
                acck[i][j] = __builtin_amdgcn_mfma_f32_16x16x32_f16(ah[i], bkl[j], acck[i][j], 0, 0, 0);
                acck[i][j] = __builtin_amdgcn_mfma_f32_16x16x32_f16(al[i], bkh[j], acck[i][j], 0, 0, 0);
            }
    }
    // C/D layout: col = lane&15, row = (lane>>4)*4 + reg
    int rbase = (lane >> 4) * 4, ccol = lane & 15;
    #pragma unroll
    for (int i = 0; i < 4; i++)
        #pragma unroll
        for (int j = 0; j < 4; j++) {
            int c = n0 + j * 16 + ccol;
            int h = c >> 6, d = c & 63;
            #pragma unroll
            for (int r = 0; r < 4; r++) {
                int rg = m0 + i * 16 + rbase + r;
                int bb = rg >> 12, l = rg & 4095;
                size_t off = ((size_t)(bb * 8 + h) * 4096 + l) * 64 + d;
                Q[off] = accq[i][j][r];
                K[off] = acck[i][j][r];
            }
        }
}

// ---- V GEMM via fp16 MFMA (hi plane only), full-head writes -------------------
__global__ __launch_bounds__(256, 3) void vgemm_kernel(
    const unsigned short* __restrict__ Xh,
    const unsigned short* __restrict__ BTh,   // WT z=2 (hi)
    float* __restrict__ V)
{
    int wave = threadIdx.x >> 6;
    int lane = threadIdx.x & 63;
    int m0 = blockIdx.x * 128 + (wave >> 1) * 64;
    int n0 = blockIdx.y * 128 + (wave & 1) * 64;
    int fr = lane & 15;
    int kq = (lane >> 4) * 8;

    float4v acc[4][4];
    #pragma unroll
    for (int i = 0; i < 4; i++)
        #pragma unroll
        for (int j = 0; j < 4; j++) acc[i][j] = (float4v){0.f, 0.f, 0.f, 0.f};

    for (int k0 = 0; k0 < 512; k0 += 32) {
        half8 a[4], b[4];
        #pragma unroll
        for (int i = 0; i < 4; i++)
            a[i] = *(const half8*)(Xh + (size_t)(m0 + i * 16 + fr) * 512 + k0 + kq);
        #pragma unroll
        for (int j = 0; j < 4; j++)
            b[j] = *(const half8*)(BTh + (size_t)(n0 + j * 16 + fr) * 512 + k0 + kq);
        #pragma unroll
        for (int i = 0; i < 4; i++)
            #pragma unroll
            for (int j = 0; j < 4; j++)
                acc[i][j] = __builtin_amdgcn_mfma_f32_16x16x32_f16(a[i], b[j], acc[i][j], 0, 0, 0);
    }
    int rbase = (lane >> 4) * 4, ccol = lane & 15;
    #pragma unroll
    for (int i = 0; i < 4; i++)
        #pragma unroll
        for (int j = 0; j < 4; j++) {
            int c = n0 + j * 16 + ccol;
            int h = c >> 6, d = c & 63;
            #pragma unroll
            for (int r = 0; r < 4; r++) {
                int rg = m0 + i * 16 + rbase + r;
                int bb = rg >> 12, l = rg & 4095;
                V[((size_t)(bb * 8 + h) * 4096 + l) * 64 + d] = acc[i][j][r];
            }
        }
}

// ---------------- M = max_s(q.k_samp) - mean_s(q.k_samp), fp32 ----------------
// All 12 gather loads pre-issued into registers, then consumed.
__global__ __launch_bounds__(256) void m_kernel(
    const float* __restrict__ Q, const float* __restrict__ K,
    const int* __restrict__ idx, float* __restrict__ M)
{
    int inst = blockIdx.x * 4 + (threadIdx.x >> 6);   // bh*4096 + l
    int lane = threadIdx.x & 63;
    int g = lane >> 4;
    int t = lane & 15;
    int bh = inst >> 12;
    int l = inst & 4095;
    float4 qv = *(const float4*)(Q + (size_t)inst * 64 + t * 4);
    const float* kb = K + (size_t)bh * 4096 * 64;
    const int* irow = idx + (size_t)l * SS;
    int jv[12];
    #pragma unroll
    for (int it = 0; it < 12; it++) {
        int s = it * 4 + g;
        jv[it] = irow[(s < SS) ? s : 0];
    }
    float4 kvv[12];
    #pragma unroll
    for (int it = 0; it < 12; it++)
        kvv[it] = *(const float4*)(kb + (size_t)jv[it] * 64 + t * 4);
    float maxv = -1e30f, sum = 0.f;
    #pragma unroll
    for (int it = 0; it < 12; it++) {
        int s = it * 4 + g;
        bool valid = (s < SS);
        float4 kv = kvv[it];
        float p = qv.x * kv.x + qv.y * kv.y + qv.z * kv.z + qv.w * kv.w;
        p += __shfl_xor(p, 1, 64);
        p += __shfl_xor(p, 2, 64);
        p += __shfl_xor(p, 4, 64);
        p += __shfl_xor(p, 8, 64);
        if (valid) { maxv = fmaxf(maxv, p); sum += p; }
    }
    maxv = fmaxf(maxv, __shfl_xor(maxv, 16, 64));
    maxv = fmaxf(maxv, __shfl_xor(maxv, 32, 64));
    sum += __shfl_xor(sum, 16, 64);
    sum += __shfl_xor(sum, 32, 64);
    if (lane == 0) M[inst] = maxv - sum * (1.f / 45.f);
}

// ---------------- per-(b,h) top-45 of M over L (wave-shuffle reduce) -----------
__global__ __launch_bounds__(256) void topk_kernel(
    const float* __restrict__ M, int* __restrict__ tidx)
{
    int bh = blockIdx.x;
    __shared__ float vals[4096];
    __shared__ float wv[4];
    __shared__ int wi[4];
    int tid = threadIdx.x;
    int lane = tid & 63, w = tid >> 6;
    for (int i = tid; i < 4096; i += 256) vals[i] = M[(size_t)bh * 4096 + i];
    __syncthreads();
    for (int it = 0; it < SS; it++) {
        float bv = -1e38f; int bi = 0x7fffffff;
        for (int i = tid; i < 4096; i += 256) {
            float v = vals[i];
            if (v > bv) { bv = v; bi = i; }
        }
        #pragma unroll
        for (int s = 32; s > 0; s >>= 1) {
            float v2 = __shfl_xor(bv, s, 64);
            int i2 = __shfl_xor(bi, s, 64);
            if (v2 > bv || (v2 == bv && i2 < bi)) { bv = v2; bi = i2; }
        }
        if (lane == 0) { wv[w] = bv; wi[w] = bi; }
        __syncthreads();
        if (tid == 0) {
            float b0 = wv[0]; int i0 = wi[0];
            #pragma unroll
            for (int k = 1; k < 4; k++)
                if (wv[k] > b0 || (wv[k] == b0 && wi[k] < i0)) { b0 = wv[k]; i0 = wi[k]; }
            tidx[bh * SS + it] = i0;
            vals[i0] = -1e38f;
        }
        __syncthreads();
    }
}

// ---------------- v mean partials over l-chunks --------------------------------
__global__ __launch_bounds__(256) void vmean_part_kernel(
    const float* __restrict__ V, float* __restrict__ vmp)
{
    int bh = blockIdx.x;
    int chunk = blockIdx.y;
    int d = threadIdx.x & 63, part = threadIdx.x >> 6;
    const float* vb = V + ((size_t)bh * 4096 + chunk * 256) * 64;
    float s = 0.f;
    for (int l = part; l < 256; l += 4) s += vb[(size_t)l * 64 + d];
    __shared__ float red[4][64];
    red[part][d] = s;
    __syncthreads();
    if (part == 0) vmp[((size_t)bh * 16 + chunk) * 64 + d] = red[0][d] + red[1][d] + red[2][d] + red[3][d];
}

// ---------------- vmean finalize + base_b = mean_row @ Wo ----------------------
__global__ __launch_bounds__(256) void base_kernel(
    const float* __restrict__ vmp, const float* __restrict__ Wo,
    float* __restrict__ vmean, float* __restrict__ base)
{
    int b = blockIdx.x;
    __shared__ float vmS[512];
    int tid = threadIdx.x;
    for (int i = tid; i < 512; i += 256) {
        int h = i >> 6, d = i & 63;
        float s = 0.f;
        #pragma unroll
        for (int c = 0; c < 16; c++) s += vmp[((size_t)(b * 8 + h) * 16 + c) * 64 + d];
        s *= (1.f / 4096.f);
        vmS[i] = s;
        vmean[(size_t)b * 512 + i] = s;
    }
    __syncthreads();
    for (int j = tid; j < 512; j += 256) {
        float s = 0.f;
        for (int i = 0; i < 512; i++) s += vmS[i] * Wo[(size_t)i * 512 + j];
        base[(size_t)b * 512 + j] = s;
    }
}

// ---------------- zero ctx accumulator -----------------------------------------
__global__ __launch_bounds__(256) void zeroctx_kernel(float* __restrict__ ctx)
{
    ctx[blockIdx.x * 256 + threadIdx.x] = 0.f;   // grid 360 -> 92,160
}

// ---------------- scores = Qr . k * scale ---------------------------------------
__global__ __launch_bounds__(256) void scores_kernel(
    const float* __restrict__ Q, const float* __restrict__ K,
    const int* __restrict__ tidx, float* __restrict__ attn)
{
    int ltile = blockIdx.x;
    int bh = blockIdx.y;
    __shared__ float Qs[48][68];
    __shared__ float Ks[64][68];
    __shared__ int tS[48];
    int tid = threadIdx.x;
    if (tid < 48) tS[tid] = (tid < SS) ? tidx[bh * SS + tid] : 0;
    __syncthreads();
    int lane = tid & 63, w = tid >> 6;
    for (int u = w; u < 48; u += 4)
        Qs[u][lane] = Q[((size_t)bh * 4096 + tS[u]) * 64 + lane];
    for (int r = w; r < 64; r += 4)
        Ks[r][lane] = K[((size_t)bh * 4096 + ltile * 64 + r) * 64 + lane];
    __syncthreads();
    if (tid < 192) {
        int ug = tid >> 4, lg = tid & 15;
        float acc[4][4];
        #pragma unroll
        for (int i = 0; i < 4; i++)
            #pragma unroll
            for (int j = 0; j < 4; j++) acc[i][j] = 0.f;
        for (int d0 = 0; d0 < 64; d0 += 4) {
            float4 a[4], b[4];
            #pragma unroll
            for (int i = 0; i < 4; i++) a[i] = *(float4*)&Qs[ug * 4 + i][d0];
            #pragma unroll
            for (int j = 0; j < 4; j++) b[j] = *(float4*)&Ks[lg * 4 + j][d0];
            #pragma unroll
            for (int i = 0; i < 4; i++)
                #pragma unroll
                for (int j = 0; j < 4; j++)
                    acc[i][j] += a[i].x * b[j].x + a[i].y * b[j].y + a[i].z * b[j].z + a[i].w * b[j].w;
        }
        const float scale = 0.125f;
        #pragma unroll
        for (int i = 0; i < 4; i++) {
            int u = ug * 4 + i;
            if (u < SS) {
                float4 r = make_float4(acc[i][0] * scale, acc[i][1] * scale,
                                       acc[i][2] * scale, acc[i][3] * scale);
                *(float4*)(attn + (size_t)(bh * SS + u) * 4096 + ltile * 64 + lg * 4) = r;
            }
        }
    }
}

// ---------------- softmax over L per (bh,u) row --------------------------------
__global__ __launch_bounds__(256) void softmax_kernel(float* __restrict__ attn)
{
    int rr = blockIdx.x;
    float* row = attn + (size_t)rr * 4096;
    int tid = threadIdx.x;
    float v[16];
    float m = -1e30f;
    #pragma unroll
    for (int i = 0; i < 16; i++) { v[i] = row[tid + 256 * i]; m = fmaxf(m, v[i]); }
    __shared__ float red[256];
    red[tid] = m; __syncthreads();
    for (int s = 128; s > 0; s >>= 1) { if (tid < s) red[tid] = fmaxf(red[tid], red[tid + s]); __syncthreads(); }
    m = red[0]; __syncthreads();
    float sum = 0.f;
    #pragma unroll
    for (int i = 0; i < 16; i++) { v[i] = __expf(v[i] - m); sum += v[i]; }
    red[tid] = sum; __syncthreads();
    for (int s = 128; s > 0; s >>= 1) { if (tid < s) red[tid] += red[tid + s]; __syncthreads(); }
    float inv = 1.f / red[0];
    #pragma unroll
    for (int i = 0; i < 16; i++) row[tid + 256 * i] = v[i] * inv;
}

// ---------------- PV: partial over 64-l chunk, atomicAdd into ctx ---------------
__global__ __launch_bounds__(256) void pv_kernel(
    const float* __restrict__ attn, const float* __restrict__ V,
    float* __restrict__ ctx)
{
    int bh = blockIdx.x;   // 32
    int ck = blockIdx.y;   // 64 chunks of 64 l
    int tid = threadIdx.x;
    int d = tid & 63, w = tid >> 6;
    float acc[12];
    #pragma unroll
    for (int j = 0; j < 12; j++) acc[j] = 0.f;
    const float* vb = V + ((size_t)bh * 4096 + ck * 64) * 64;
    const float* ab = attn + (size_t)bh * SS * 4096 + ck * 64;
    for (int li = 0; li < 64; li++) {
        float vv = vb[(size_t)li * 64 + d];
        #pragma unroll
        for (int j = 0; j < 12; j++) {
            int u = w + 4 * j;
            float a = (u < SS) ? ab[(size_t)u * 4096 + li] : 0.f;
            acc[j] += a * vv;
        }
    }
    #pragma unroll
    for (int j = 0; j < 12; j++) {
        int u = w + 4 * j;
        if (u < SS) atomicAdd(ctx + ((size_t)bh * SS + u) * 64 + d, acc[j]);
    }
}

// ---------------- delta_out[bh,u,:] = (ctx - vmean) @ Wo_h ----------------------
__global__ __launch_bounds__(256) void delta_kernel(
    const float* __restrict__ ctx, const float* __restrict__ vmean,
    const float* __restrict__ Wo, float* __restrict__ dout)
{
    int rr = blockIdx.x;          // bh*45 + u
    int bh = rr / SS;
    int h = bh & 7;
    __shared__ float dS[64];
    int tid = threadIdx.x;
    if (tid < 64)
        dS[tid] = ctx[(size_t)rr * 64 + tid] - vmean[(size_t)bh * 64 + tid];
    __syncthreads();
    for (int j = tid; j < 512; j += 256) {
        float s = 0.f;
        #pragma unroll
        for (int dd = 0; dd < 64; dd++) s += dS[dd] * Wo[(size_t)(h * 64 + dd) * 512 + j];
        dout[(size_t)rr * 512 + j] = s;
    }
}

// ---------------- fill out with per-b base row ---------------------------------
__global__ __launch_bounds__(256) void fill_kernel(
    const float4* __restrict__ base4, float4* __restrict__ out4)
{
    int i = blockIdx.x * 256 + threadIdx.x;
    int b = i >> 19;
    int j4 = i & 127;
    out4[i] = base4[b * 128 + j4];
}

// ---------------- scatter-add deltas into selected rows -------------------------
__global__ __launch_bounds__(256) void scatter_kernel(
    const float* __restrict__ dout, const int* __restrict__ tidx,
    float* __restrict__ out)
{
    int rr = blockIdx.x;
    int bh = rr / SS;
    int b = bh >> 3;
    int l = tidx[rr];
    float* orow = out + ((size_t)b * 4096 + l) * 512;
    const float* drow = dout + (size_t)rr * 512;
    for (int j = threadIdx.x; j < 512; j += 256)
        atomicAdd(orow + j, drow[j]);
}

extern "C" void kernel_launch(void* const* d_in, const int* in_sizes, int n_in,
                              void* d_out, int out_size, void* d_ws, size_t ws_size,
                              hipStream_t stream)
{
    const float* x  = (const float*)d_in[0];
    const float* Wq = (const float*)d_in[1];
    const float* Wk = (const float*)d_in[2];
    const float* Wv = (const float*)d_in[3];
    const float* Wo = (const float*)d_in[4];
    const int*  idx = (const int*)d_in[5];
    float* out = (float*)d_out;

    float* W = (float*)d_ws;
    float* Q = W;                        // 8,388,608 f
    float* K = W + 8388608;              // 8,388,608 f
    float* V = W + 16777216;             // 8,388,608 f
    // fp16 staging (live: conv -> qk3/vgemm only)
    unsigned short* xh  = (unsigned short*)(W + 25165824);  // 8,388,608 u16 -> ends 29360128
    unsigned short* xl  = (unsigned short*)(W + 29360128);  // 8,388,608 u16 -> ends 33554432
    unsigned short* WTh = (unsigned short*)(W + 33554432);  // 786,432 u16  -> ends 33947648
    unsigned short* WTl = (unsigned short*)(W + 33947648);  // 786,432 u16  -> ends 34340864
    // total 137.4 MB

    // post-projection buffers alias xh/xl (all written after vgemm/qk3 consume them)
    float* Mv    = W + 25165824;         // 131,072
    float* attn  = W + 25296896;         // 5,898,240 -> ends 31195136
    float* ctx   = W + 31195136;         // 92,160    -> ends 31287296
    float* dout  = W + 32669696;         // 737,280   -> ends 33406976
    float* vmp   = W + 33406976;         // 32,768
    float* vmean = W + 33439744;         // 2,048
    float* base  = W + 33441792;         // 2,048
    int*   tidx  = (int*)(W + 33443840); // 1,440 ints (ends 33,445,280 < 33,554,432)

    convx2_kernel<<<8192, 256, 0, stream>>>((const float4*)x, (ushort4*)xh, (ushort4*)xl);
    convw2_kernel<<<dim3(256, 3), 256, 0, stream>>>(Wq, Wk, Wv, WTh, WTl);
    qk3_kernel<<<dim3(128, 4), 256, 0, stream>>>(xh, xl, WTh, WTl, Q, K);
    vgemm_kernel<<<dim3(128, 4), 256, 0, stream>>>(xh, WTh + (size_t)2 * 512 * 512, V);
    m_kernel<<<32768, 256, 0, stream>>>(Q, K, idx, Mv);
    topk_kernel<<<32, 256, 0, stream>>>(Mv, tidx);
    vmean_part_kernel<<<dim3(32, 16), 256, 0, stream>>>(V, vmp);
    base_kernel<<<4, 256, 0, stream>>>(vmp, Wo, vmean, base);
    zeroctx_kernel<<<360, 256, 0, stream>>>(ctx);
    scores_kernel<<<dim3(64, 32), 256, 0, stream>>>(Q, K, tidx, attn);
    softmax_kernel<<<1440, 256, 0, stream>>>(attn);
    pv_kernel<<<dim3(32, 64), 256, 0, stream>>>(attn, V, ctx);
    delta_kernel<<<1440, 256, 0, stream>>>(ctx, vmean, Wo, dout);
    fill_kernel<<<8192, 256, 0, stream>>>((const float4*)base, (float4*)out);
    scatter_kernel<<<1440, 256, 0, stream>>>(dout, tidx, out);
}